// Round 4
// baseline (642.670 us; speedup 1.0000x reference)
//
#include <hip/hip_runtime.h>

// NucleiGNN fused forward: B=2048 molecules, one block (512 thr) per molecule.
// All matmuls on v_mfma_f32_16x16x32_f16 with f32 accumulation; h resident in
// C-fragment registers (transposed orientation). Weights pre-transposed +
// f16-converted into a static __device__ array. XOR-swizzled f16 LDS tiles,
// ~70KB LDS -> 2 blocks/CU.
// Round-3 changes (VALU-bound per rocprof: MfmaUtil 6%, VALUBusy 46%):
//  - edge d/exp(-d) hoisted out of the layer loop (was recomputed 6x/pair)
//  - native-instr transcendentals (v_exp_f32, v_rcp_f32, v_sqrt_f32, fast tanh)
//  - block-uniform skipping of fully-masked 16-row tiles (len in [32,64])
//  - nontemporal output stores via ext_vector types (builtin rejects HIP_vector_type)

#define NBATCH 2048
#define NATOM  64
#define NF     128
#define NLAYER 3
#define NTH    512

typedef __attribute__((ext_vector_type(8))) _Float16 f16x8;
typedef __attribute__((ext_vector_type(4))) float    f32x4;
typedef __attribute__((ext_vector_type(4))) unsigned short us4v;

// WT[f][k] as f16 bits: 15 matrices (Wq,Wk,Wv,Wo,Wf) x 3 layers, 128x128 each.
__device__ __align__(16) unsigned short g_wt[15 * NF * NF];

__device__ __forceinline__ float bf2f(unsigned short u) {
    union { unsigned int i; float f; } v; v.i = ((unsigned int)u) << 16; return v.f;
}
__device__ __forceinline__ unsigned short f2bf(float f) {
    union { float ff; unsigned int i; } v; v.ff = f;
    unsigned int x = v.i;
    if ((x & 0x7f800000u) == 0x7f800000u) return (unsigned short)(x >> 16);
    return (unsigned short)((x + 0x7fffu + ((x >> 16) & 1u)) >> 16);
}
__device__ __forceinline__ unsigned short f2h(float f) {
    union { _Float16 h; unsigned short u; } v; v.h = (_Float16)f; return v.u;
}
__device__ __forceinline__ float frcp(float x) { return __builtin_amdgcn_rcpf(x); }
__device__ __forceinline__ float fsqrt_(float x) { return __builtin_amdgcn_sqrtf(x); }
__device__ __forceinline__ float ftanh(float x) {
    // tanh(x) = 1 - 2/(exp(2x)+1); exp overflow/underflow saturates correctly
    return 1.f - 2.f * frcp(__expf(2.f * x) + 1.f);
}

template<bool BF16>
__device__ __forceinline__ float ldT(const void* p, int i) {
    if constexpr (BF16) return bf2f(((const unsigned short*)p)[i]);
    else                return ((const float*)p)[i];
}
template<bool BF16>
__device__ __forceinline__ float4 ld4T(const void* p, int i) {
    if constexpr (BF16) {
        ushort4 v = *(const ushort4*)((const unsigned short*)p + i);
        return make_float4(bf2f(v.x), bf2f(v.y), bf2f(v.z), bf2f(v.w));
    } else {
        return *(const float4*)((const float*)p + i);
    }
}

__device__ __forceinline__ bool detect_bf16(const void* Wq) {
    const unsigned int* w = (const unsigned int*)Wq;
    bool isbf = true;
    #pragma unroll
    for (int i = 0; i < 16; ++i) {
        unsigned int e = (w[i] >> 7) & 0xFFu;   // low-bf16 exponent if bf16-packed
        isbf = isbf && (e >= 0x60u && e <= 0x7Eu);
    }
    return isbf;
}

// ---- weight transpose + f16 convert: WT[f][k] = (f16)W[k][f] into g_wt ----
__global__ __launch_bounds__(256)
void transpose_w(const void* Wq_, const void* Wk_, const void* Wv_,
                 const void* Wo_, const void* Wf_)
{
    const bool isbf = detect_bf16(Wq_);
    __shared__ unsigned short tile[128 * 136];
    const int m = blockIdx.x, a = m / 3, ly = m % 3, t = threadIdx.x;
    const void* src = (a == 0 ? Wq_ : a == 1 ? Wk_ : a == 2 ? Wv_ : a == 3 ? Wo_ : Wf_);
    unsigned short* dst = g_wt + m * 16384;
    #pragma unroll
    for (int i = 0; i < 16; ++i) {
        int e = (i * 256 + t) * 4;          // elements e..e+3 = row r, cols c0..c0+3
        int r = e >> 7, c0 = e & 127;
        float4 v;
        if (isbf) {
            ushort4 u = *(const ushort4*)((const unsigned short*)src + ly * 16384 + e);
            v = make_float4(bf2f(u.x), bf2f(u.y), bf2f(u.z), bf2f(u.w));
        } else {
            v = *(const float4*)((const float*)src + ly * 16384 + e);
        }
        tile[(c0+0)*136 + r] = f2h(v.x); tile[(c0+1)*136 + r] = f2h(v.y);
        tile[(c0+2)*136 + r] = f2h(v.z); tile[(c0+3)*136 + r] = f2h(v.w);
    }
    __syncthreads();
    #pragma unroll
    for (int i = 0; i < 16; ++i) {
        int e = (i * 256 + t) * 4;
        int f = e >> 7, k0 = e & 127;
        *(ushort4*)(dst + e) = *(const ushort4*)&tile[f * 136 + k0];
    }
}

// Y^T = W^T * X^T for one 16-row f-stripe per wave, 4 n-frags (tiles >= ntile
// are fully masked -> skipped; their acc stays 0 and gets stored as zeros).
// A-frag: WT rows (global, 16B); B-frag: X rows in swizzled f16 LDS (16B).
__device__ __forceinline__ void mm_t(const unsigned short* __restrict__ wtp,
                                     const char* __restrict__ X,
                                     f32x4 (&acc)[4], int c, int g, int ntile)
{
    f16x8 a4[4];
    #pragma unroll
    for (int ks = 0; ks < 4; ++ks)
        a4[ks] = *(const f16x8*)(const void*)(wtp + c * NF + ks * 32 + 8 * g);
    #pragma unroll
    for (int ks = 0; ks < 4; ++ks) {
        #pragma unroll
        for (int nf = 0; nf < 4; ++nf) {
            if (nf >= ntile) continue;   // block-uniform branch
            const int row = nf * 16 + c;
            f16x8 bfr = *(const f16x8*)(X + row * 256 + ((ks * 64 + 16 * g) ^ ((row & 7) << 4)));
            acc[nf] = __builtin_amdgcn_mfma_f32_16x16x32_f16(a4[ks], bfr, acc[nf], 0, 0, 0);
        }
    }
}

// Row mean/var of frag-resident h^T (lane: n = nf*16+c; 4 f-vals each).
// Includes two __syncthreads() (first one also orders prior LDS reads).
__device__ __forceinline__ void ln_stats(const f32x4 (&h)[4],
                                         float* __restrict__ part, float* __restrict__ part2,
                                         float* __restrict__ mu_s, float* __restrict__ rs_s,
                                         int t, int w, int c)
{
    #pragma unroll
    for (int nf = 0; nf < 4; ++nf) {
        float s  = h[nf][0] + h[nf][1] + h[nf][2] + h[nf][3];
        float s2 = h[nf][0]*h[nf][0] + h[nf][1]*h[nf][1] + h[nf][2]*h[nf][2] + h[nf][3]*h[nf][3];
        s  += __shfl_xor(s, 16);  s  += __shfl_xor(s, 32);
        s2 += __shfl_xor(s2, 16); s2 += __shfl_xor(s2, 32);
        if ((t & 63) < 16) { const int n = nf * 16 + c; part[n*9 + w] = s; part2[n*9 + w] = s2; }
    }
    __syncthreads();
    if (t < 64) {
        float s = 0.f, s2 = 0.f;
        #pragma unroll
        for (int q = 0; q < 8; ++q) { s += part[t*9 + q]; s2 += part2[t*9 + q]; }
        float mu = s * (1.f / 128.f);
        float var = s2 * (1.f / 128.f) - mu * mu;
        mu_s[t] = mu; rs_s[t] = rsqrtf(fmaxf(var, 0.f) + 1e-5f);
    }
    __syncthreads();
}

__device__ __forceinline__ void st_rows(char* __restrict__ B, const f32x4 (&acc)[4],
                                        int c, int g, int f0)
{
    #pragma unroll
    for (int nf = 0; nf < 4; ++nf) {
        const int n = nf * 16 + c;
        ushort4 o = make_ushort4(f2h(acc[nf][0]), f2h(acc[nf][1]),
                                 f2h(acc[nf][2]), f2h(acc[nf][3]));
        *(ushort4*)(B + n * 256 + ((2 * (f0 + 4 * g)) ^ ((n & 7) << 4))) = o;
    }
}

__device__ __forceinline__ void st_vt(char* __restrict__ VT_, const f32x4 (&acc)[4],
                                      int c, int g, int f0)
{
    #pragma unroll
    for (int nf = 0; nf < 4; ++nf) {
        #pragma unroll
        for (int r = 0; r < 4; ++r) {
            const int fr = f0 + 4 * g + r;
            *(unsigned short*)(VT_ + fr * 128 + ((2 * (nf * 16 + c)) ^ ((fr & 7) << 4)))
                = f2h(acc[nf][r]);
        }
    }
}

template<bool BF16>
__global__ __launch_bounds__(NTH, 4)
void gnn_mfma(const void* __restrict__ coords,
              const int*  __restrict__ species,
              const unsigned char* __restrict__ maskraw,
              const void* __restrict__ embed,
              const void* __restrict__ Wq,      // dtype-detect only
              const void* __restrict__ We,
              const void* __restrict__ bfb,
              void* __restrict__ out)
{
    if (detect_bf16(Wq) != BF16) return;   // block-uniform early exit

    extern __shared__ char smem2[];
    char* HN = smem2;                 // [64][128] f16 swz : hn, then msg
    char* QB = HN + 16384;            // [64][128] f16 swz : q, then P
    char* KB = QB + 16384;            // [64][128] f16 swz : k
    char* VT = KB + 16384;            // [128][64] f16 swz : v^T (f-major)
    float* cs    = (float*)(VT + 16384);   // 64*4
    float* wel   = cs + 256;               // 48
    float* mu_s  = wel + 48;               // 64
    float* rs_s  = mu_s + 64;              // 64
    float* part  = rs_s + 64;              // 64*9
    float* part2 = part + 576;             // 64*9
    int*   lenp  = (int*)(part2 + 576);

    const int t = threadIdx.x, b = blockIdx.x;
    const int w = t >> 6, la = t & 63, g = la >> 4, c = la & 15;
    const int f0 = w * 16;
    const f32x4 z4 = {0.f, 0.f, 0.f, 0.f};

    if (t < 64) {
        cs[t*4+0] = ldT<BF16>(coords, (b * NATOM + t) * 3 + 0);
        cs[t*4+1] = ldT<BF16>(coords, (b * NATOM + t) * 3 + 1);
        cs[t*4+2] = ldT<BF16>(coords, (b * NATOM + t) * 3 + 2);
    }
    if (t >= 64 && t < 64 + 42) wel[t - 64] = ldT<BF16>(We, t - 64);
    if (t < 64) {
        unsigned int w0 = *(const unsigned int*)maskraw;
        bool fm;
        if (w0 == 1u)               fm = ((const int*)maskraw)[b * NATOM + t] != 0;
        else if (w0 == 0x01010101u) fm = maskraw[b * NATOM + t] != 0;
        else if (w0 == 0x3F800000u) fm = ((const float*)maskraw)[b * NATOM + t] != 0.f;
        else                        fm = ((const unsigned short*)maskraw)[b * NATOM + t] != 0;
        unsigned long long bal = __ballot(fm);
        if (t == 0) *lenp = (int)__popcll(bal);
    }

    // h^T resident in C-frag layout: hst[nf][r] = h[n = nf*16+c][f = f0+4g+r]
    f32x4 hst[4];
    #pragma unroll
    for (int nf = 0; nf < 4; ++nf) {
        const int n = nf * 16 + c;
        const int sp = species[b * NATOM + n];
        float4 ev = ld4T<BF16>(embed, (sp - 1) * NF + f0 + 4 * g);
        hst[nf][0] = ev.x; hst[nf][1] = ev.y; hst[nf][2] = ev.z; hst[nf][3] = ev.w;
    }
    __syncthreads();
    const int len = *lenp;
    const int ntile = (len + 15) >> 4;    // block-uniform active 16-row tiles
    #pragma unroll
    for (int nf = 0; nf < 4; ++nf)
        if (nf * 16 + c >= len) hst[nf] = z4;

    const int hd = w >> 2;            // attention: wave -> (head, n-stripe)
    const int n0 = (w & 3) * 16;
    const bool wactive = (n0 < len);  // wave-uniform: this n-stripe has live rows

    // ---- layer-invariant edge geometry, hoisted (d and exp(-d) per (n,m)) ----
    // mapping matches the QK^T S^T fragment: n = n0+c, m = mf*16 + 4g + r
    f32x4 d_e[4], et_e[4];
    {
        const float cnx = cs[(n0+c)*4+0], cny = cs[(n0+c)*4+1], cnz = cs[(n0+c)*4+2];
        #pragma unroll
        for (int mf = 0; mf < 4; ++mf) {
            #pragma unroll
            for (int r = 0; r < 4; ++r) {
                const int m = mf * 16 + 4 * g + r;
                float dx = cnx - cs[m*4+0];
                float dy = cny - cs[m*4+1];
                float dz = cnz - cs[m*4+2];
                float d = fsqrt_(dx*dx + dy*dy + dz*dz + 1e-12f);
                d_e[mf][r]  = d;
                et_e[mf][r] = __expf(-d);
            }
        }
    }

    for (int ly = 0; ly < NLAYER; ++ly) {
        const unsigned short* wqT = g_wt + (0 * 3 + ly) * 16384;
        const unsigned short* wkT = g_wt + (1 * 3 + ly) * 16384;
        const unsigned short* wvT = g_wt + (2 * 3 + ly) * 16384;
        const unsigned short* woT = g_wt + (3 * 3 + ly) * 16384;
        const unsigned short* wfT = g_wt + (4 * 3 + ly) * 16384;

        // ---- LN1 -> HN (f16, swizzled) ----
        ln_stats(hst, part, part2, mu_s, rs_s, t, w, c);
        #pragma unroll
        for (int nf = 0; nf < 4; ++nf) {
            const int n = nf * 16 + c;
            const float mu = mu_s[n], rs = rs_s[n];
            ushort4 o = make_ushort4(f2h((hst[nf][0]-mu)*rs), f2h((hst[nf][1]-mu)*rs),
                                     f2h((hst[nf][2]-mu)*rs), f2h((hst[nf][3]-mu)*rs));
            *(ushort4*)(HN + n * 256 + ((2 * (f0 + 4 * g)) ^ ((n & 7) << 4))) = o;
        }
        __syncthreads();

        // ---- q,k,v = LN(h) @ W{q,k,v} ----
        {
            f32x4 acc[4] = {z4, z4, z4, z4};
            mm_t(wqT + f0 * NF, HN, acc, c, g, ntile);
            st_rows(QB, acc, c, g, f0);
            acc[0]=z4; acc[1]=z4; acc[2]=z4; acc[3]=z4;
            mm_t(wkT + f0 * NF, HN, acc, c, g, ntile);
            st_rows(KB, acc, c, g, f0);
            acc[0]=z4; acc[1]=z4; acc[2]=z4; acc[3]=z4;
            mm_t(wvT + f0 * NF, HN, acc, c, g, ntile);
            st_vt(VT, acc, c, g, f0);
        }
        __syncthreads();

        // ---- swapped QK^T: sacc[mf] = S^T[m][n], m = mf*16+4g+r, n = n0+c ----
        f32x4 sacc[4] = {z4, z4, z4, z4};
        if (wactive) {
            #pragma unroll
            for (int ks = 0; ks < 2; ++ks) {
                const int bc = hd * 128 + ks * 64 + 16 * g;
                const int qrow = n0 + c;
                f16x8 bq = *(const f16x8*)(QB + qrow * 256 + (bc ^ ((qrow & 7) << 4)));
                #pragma unroll
                for (int mf = 0; mf < 4; ++mf) {
                    if (mf >= ntile) continue;
                    const int krow = mf * 16 + c;
                    f16x8 ak = *(const f16x8*)(KB + krow * 256 + (bc ^ ((krow & 7) << 4)));
                    sacc[mf] = __builtin_amdgcn_mfma_f32_16x16x32_f16(ak, bq, sacc[mf], 0, 0, 0);
                }
            }
            // edges + masked softmax over m (lanes sharing n: xor 16, 32)
            float we_[7];
            #pragma unroll
            for (int e = 0; e < 7; ++e) we_[e] = wel[ly * 14 + e * 2 + hd];
            const float cnx = cs[(n0+c)*4+0], cny = cs[(n0+c)*4+1], cnz = cs[(n0+c)*4+2];
            float mx = -1e30f;
            #pragma unroll
            for (int mf = 0; mf < 4; ++mf) {
                if (mf < ntile) {
                    #pragma unroll
                    for (int r = 0; r < 4; ++r) {
                        const int m = mf * 16 + 4 * g + r;
                        float dx = cnx - cs[m*4+0];
                        float dy = cny - cs[m*4+1];
                        float dz = cnz - cs[m*4+2];
                        const float d = d_e[mf][r], et = et_e[mf][r];
                        float s1 = frcp(1.f + 7.38905609893065f   * et);  // sigmoid(d-2)
                        float s2 = frcp(1.f + 54.598150033144236f * et);  // sigmoid(d-4)
                        float s3 = frcp(1.f + 403.4287934927351f  * et);  // sigmoid(d-6)
                        float val = sacc[mf][r] * 0.125f
                                  + dx*we_[0] + dy*we_[1] + dz*we_[2] + d*we_[3]
                                  + s1*we_[4] + s2*we_[5] + s3*we_[6];
                        if (m >= len) val = -1e30f;
                        sacc[mf][r] = val;
                        mx = fmaxf(mx, val);
                    }
                } else {
                    sacc[mf] = (f32x4){-1e30f, -1e30f, -1e30f, -1e30f};
                }
            }
            mx = fmaxf(mx, __shfl_xor(mx, 16));
            mx = fmaxf(mx, __shfl_xor(mx, 32));
            float sm = 0.f;
            #pragma unroll
            for (int mf = 0; mf < 4; ++mf) {
                if (mf < ntile) {
                    #pragma unroll
                    for (int r = 0; r < 4; ++r) {
                        float e = __expf(sacc[mf][r] - mx);
                        sacc[mf][r] = e; sm += e;
                    }
                } else {
                    sacc[mf] = z4;   // masked tiles: zero probability
                }
            }
            sm += __shfl_xor(sm, 16);
            sm += __shfl_xor(sm, 32);
            const float inv = frcp(sm);        // >= 1 valid entry per live row
            #pragma unroll
            for (int mf = 0; mf < 4; ++mf) {
                sacc[mf][0] *= inv; sacc[mf][1] *= inv;
                sacc[mf][2] *= inv; sacc[mf][3] *= inv;
            }
        }
        __syncthreads();                       // all q/k reads complete
        if (wactive) {
            #pragma unroll
            for (int mf = 0; mf < 4; ++mf) {   // P[n][m] f16 into QB
                const int prow = n0 + c;
                ushort4 o = make_ushort4(f2h(sacc[mf][0]), f2h(sacc[mf][1]),
                                         f2h(sacc[mf][2]), f2h(sacc[mf][3]));
                *(ushort4*)(QB + prow * 256 + ((hd * 128 + mf * 32 + 8 * g) ^ ((prow & 7) << 4))) = o;
            }
        }
        __syncthreads();

        // ---- PV: msg^T = V^T * P^T ; msg[n][f] into HN ----
        {
            const int d0 = (w & 3) * 16;
            f32x4 macc[4] = {z4, z4, z4, z4};
            #pragma unroll
            for (int ks = 0; ks < 2; ++ks) {
                if (ks * 32 >= len) continue;          // m-slice fully masked
                const int vrow = hd * 64 + d0 + c;
                f16x8 av = *(const f16x8*)(VT + vrow * 128 + ((ks * 64 + 16 * g) ^ ((vrow & 7) << 4)));
                #pragma unroll
                for (int nf = 0; nf < 4; ++nf) {
                    if (nf >= ntile) continue;
                    const int prow = nf * 16 + c;
                    f16x8 bp = *(const f16x8*)(QB + prow * 256 +
                                 ((hd * 128 + ks * 64 + 16 * g) ^ ((prow & 7) << 4)));
                    macc[nf] = __builtin_amdgcn_mfma_f32_16x16x32_f16(av, bp, macc[nf], 0, 0, 0);
                }
            }
            #pragma unroll
            for (int nf = 0; nf < 4; ++nf) {
                const int n = nf * 16 + c;
                ushort4 o = make_ushort4(f2h(macc[nf][0]), f2h(macc[nf][1]),
                                         f2h(macc[nf][2]), f2h(macc[nf][3]));
                *(ushort4*)(HN + n * 256 + ((hd * 128 + (w & 3) * 32 + 8 * g) ^ ((n & 7) << 4))) = o;
            }
        }
        __syncthreads();

        // ---- h += msg @ Wo ----
        {
            f32x4 acc[4] = {z4, z4, z4, z4};
            mm_t(woT + f0 * NF, HN, acc, c, g, ntile);
            #pragma unroll
            for (int nf = 0; nf < 4; ++nf) hst[nf] += acc[nf];
        }
        // ---- LN2 -> HN (ln_stats' first barrier orders all Wo reads first) ----
        ln_stats(hst, part, part2, mu_s, rs_s, t, w, c);
        #pragma unroll
        for (int nf = 0; nf < 4; ++nf) {
            const int n = nf * 16 + c;
            const float mu = mu_s[n], rs = rs_s[n];
            ushort4 o = make_ushort4(f2h((hst[nf][0]-mu)*rs), f2h((hst[nf][1]-mu)*rs),
                                     f2h((hst[nf][2]-mu)*rs), f2h((hst[nf][3]-mu)*rs));
            *(ushort4*)(HN + n * 256 + ((2 * (f0 + 4 * g)) ^ ((n & 7) << 4))) = o;
        }
        __syncthreads();
        // ---- h += tanh(LN2(h) @ Wf + bf) ----
        {
            f32x4 acc[4] = {z4, z4, z4, z4};
            mm_t(wfT + f0 * NF, HN, acc, c, g, ntile);
            float4 bv = ld4T<BF16>(bfb, ly * NF + f0 + 4 * g);
            #pragma unroll
            for (int nf = 0; nf < 4; ++nf) {
                if (nf >= ntile) continue;     // masked rows stay zero
                hst[nf][0] += ftanh(acc[nf][0] + bv.x);
                hst[nf][1] += ftanh(acc[nf][1] + bv.y);
                hst[nf][2] += ftanh(acc[nf][2] + bv.z);
                hst[nf][3] += ftanh(acc[nf][3] + bv.w);
            }
        }
        #pragma unroll
        for (int nf = 0; nf < 4; ++nf)
            if (nf * 16 + c >= len) hst[nf] = z4;
        // next iteration's ln_stats barrier orders Wf reads vs HN rewrite
    }

    // ---- out = LN(h), in the input dtype (nontemporal: don't pollute L2) ----
    ln_stats(hst, part, part2, mu_s, rs_s, t, w, c);
    #pragma unroll
    for (int nf = 0; nf < 4; ++nf) {
        const int n = nf * 16 + c;
        const float mu = mu_s[n], rs = rs_s[n];
        const int idx = (b * NATOM + n) * NF + f0 + 4 * g;
        if constexpr (BF16) {
            us4v o = { f2bf((hst[nf][0]-mu)*rs), f2bf((hst[nf][1]-mu)*rs),
                       f2bf((hst[nf][2]-mu)*rs), f2bf((hst[nf][3]-mu)*rs) };
            __builtin_nontemporal_store(o, (us4v*)((unsigned short*)out + idx));
        } else {
            f32x4 o = { (hst[nf][0]-mu)*rs, (hst[nf][1]-mu)*rs,
                        (hst[nf][2]-mu)*rs, (hst[nf][3]-mu)*rs };
            __builtin_nontemporal_store(o, (f32x4*)((float*)out + idx));
        }
    }
}

static constexpr size_t SMEM2_BYTES =
    4 * 16384 + (256 + 48 + 64 + 64 + 576 + 576 + 4) * sizeof(float);   // 71888

extern "C" void kernel_launch(void* const* d_in, const int* in_sizes, int n_in,
                              void* d_out, int out_size, void* d_ws, size_t ws_size,
                              hipStream_t stream) {
    const void*           coords  = d_in[0];
    const int*            species = (const int*)d_in[1];
    const unsigned char*  maskraw = (const unsigned char*)d_in[2];
    const void*           embed   = d_in[3];
    const void*           Wq      = d_in[4];
    const void*           Wk      = d_in[5];
    const void*           Wv      = d_in[6];
    const void*           Wo      = d_in[7];
    const void*           We      = d_in[8];
    const void*           Wf      = d_in[9];
    const void*           bfb     = d_in[10];
    (void)d_ws; (void)ws_size; (void)in_sizes; (void)n_in; (void)out_size;

    (void)hipFuncSetAttribute((const void*)gnn_mfma<false>,
                              hipFuncAttributeMaxDynamicSharedMemorySize,
                              (int)SMEM2_BYTES);
    (void)hipFuncSetAttribute((const void*)gnn_mfma<true>,
                              hipFuncAttributeMaxDynamicSharedMemorySize,
                              (int)SMEM2_BYTES);

    transpose_w<<<dim3(15), dim3(256), 0, stream>>>(Wq, Wk, Wv, Wo, Wf);
    gnn_mfma<false><<<dim3(NBATCH), dim3(NTH), SMEM2_BYTES, stream>>>(
        coords, species, maskraw, embed, Wq, We, bfb, d_out);
    gnn_mfma<true><<<dim3(NBATCH), dim3(NTH), SMEM2_BYTES, stream>>>(
        coords, species, maskraw, embed, Wq, We, bfb, d_out);
}

// Round 5
// 516.848 us; speedup vs baseline: 1.2434x; 1.2434x over previous
//
#include <hip/hip_runtime.h>

// NucleiGNN fused forward: B=2048 molecules, one block (512 thr) per molecule.
// All matmuls on v_mfma_f32_16x16x32_f16 with f32 accumulation; h resident in
// C-fragment registers (transposed orientation). Weights pre-transposed +
// f16-converted into a static __device__ array. XOR-swizzled f16 LDS tiles,
// ~70KB LDS -> 2 blocks/CU.
// Round-5: fix scratch-spill regression (FETCH/WRITE ~800MB symmetric, VGPR=64):
//  - amdgpu_waves_per_eu(4,4): occupancy is LDS-capped at 4 waves/EU anyway;
//    tells RA the truth -> 128-VGPR budget, fragment arrays stay in registers
//  - d/exp(-d) hoist reverted (was +32 always-live regs -> spilled every layer)
//  - kept: native transcendentals, masked-tile skipping, NT output stores

#define NBATCH 2048
#define NATOM  64
#define NF     128
#define NLAYER 3
#define NTH    512

typedef __attribute__((ext_vector_type(8))) _Float16 f16x8;
typedef __attribute__((ext_vector_type(4))) float    f32x4;
typedef __attribute__((ext_vector_type(4))) unsigned short us4v;

// WT[f][k] as f16 bits: 15 matrices (Wq,Wk,Wv,Wo,Wf) x 3 layers, 128x128 each.
__device__ __align__(16) unsigned short g_wt[15 * NF * NF];

__device__ __forceinline__ float bf2f(unsigned short u) {
    union { unsigned int i; float f; } v; v.i = ((unsigned int)u) << 16; return v.f;
}
__device__ __forceinline__ unsigned short f2bf(float f) {
    union { float ff; unsigned int i; } v; v.ff = f;
    unsigned int x = v.i;
    if ((x & 0x7f800000u) == 0x7f800000u) return (unsigned short)(x >> 16);
    return (unsigned short)((x + 0x7fffu + ((x >> 16) & 1u)) >> 16);
}
__device__ __forceinline__ unsigned short f2h(float f) {
    union { _Float16 h; unsigned short u; } v; v.h = (_Float16)f; return v.u;
}
__device__ __forceinline__ float frcp(float x) { return __builtin_amdgcn_rcpf(x); }
__device__ __forceinline__ float fsqrt_(float x) { return __builtin_amdgcn_sqrtf(x); }
__device__ __forceinline__ float ftanh(float x) {
    // tanh(x) = 1 - 2/(exp(2x)+1); exp overflow/underflow saturates correctly
    return 1.f - 2.f * frcp(__expf(2.f * x) + 1.f);
}

template<bool BF16>
__device__ __forceinline__ float ldT(const void* p, int i) {
    if constexpr (BF16) return bf2f(((const unsigned short*)p)[i]);
    else                return ((const float*)p)[i];
}
template<bool BF16>
__device__ __forceinline__ float4 ld4T(const void* p, int i) {
    if constexpr (BF16) {
        ushort4 v = *(const ushort4*)((const unsigned short*)p + i);
        return make_float4(bf2f(v.x), bf2f(v.y), bf2f(v.z), bf2f(v.w));
    } else {
        return *(const float4*)((const float*)p + i);
    }
}

__device__ __forceinline__ bool detect_bf16(const void* Wq) {
    const unsigned int* w = (const unsigned int*)Wq;
    bool isbf = true;
    #pragma unroll
    for (int i = 0; i < 16; ++i) {
        unsigned int e = (w[i] >> 7) & 0xFFu;   // low-bf16 exponent if bf16-packed
        isbf = isbf && (e >= 0x60u && e <= 0x7Eu);
    }
    return isbf;
}

// ---- weight transpose + f16 convert: WT[f][k] = (f16)W[k][f] into g_wt ----
__global__ __launch_bounds__(256)
void transpose_w(const void* Wq_, const void* Wk_, const void* Wv_,
                 const void* Wo_, const void* Wf_)
{
    const bool isbf = detect_bf16(Wq_);
    __shared__ unsigned short tile[128 * 136];
    const int m = blockIdx.x, a = m / 3, ly = m % 3, t = threadIdx.x;
    const void* src = (a == 0 ? Wq_ : a == 1 ? Wk_ : a == 2 ? Wv_ : a == 3 ? Wo_ : Wf_);
    unsigned short* dst = g_wt + m * 16384;
    #pragma unroll
    for (int i = 0; i < 16; ++i) {
        int e = (i * 256 + t) * 4;          // elements e..e+3 = row r, cols c0..c0+3
        int r = e >> 7, c0 = e & 127;
        float4 v;
        if (isbf) {
            ushort4 u = *(const ushort4*)((const unsigned short*)src + ly * 16384 + e);
            v = make_float4(bf2f(u.x), bf2f(u.y), bf2f(u.z), bf2f(u.w));
        } else {
            v = *(const float4*)((const float*)src + ly * 16384 + e);
        }
        tile[(c0+0)*136 + r] = f2h(v.x); tile[(c0+1)*136 + r] = f2h(v.y);
        tile[(c0+2)*136 + r] = f2h(v.z); tile[(c0+3)*136 + r] = f2h(v.w);
    }
    __syncthreads();
    #pragma unroll
    for (int i = 0; i < 16; ++i) {
        int e = (i * 256 + t) * 4;
        int f = e >> 7, k0 = e & 127;
        *(ushort4*)(dst + e) = *(const ushort4*)&tile[f * 136 + k0];
    }
}

// Y^T = W^T * X^T for one 16-row f-stripe per wave, 4 n-frags (tiles >= ntile
// are fully masked -> skipped; their acc stays 0 and gets stored as zeros).
// A-frag: WT rows (global, 16B); B-frag: X rows in swizzled f16 LDS (16B).
__device__ __forceinline__ void mm_t(const unsigned short* __restrict__ wtp,
                                     const char* __restrict__ X,
                                     f32x4 (&acc)[4], int c, int g, int ntile)
{
    f16x8 a4[4];
    #pragma unroll
    for (int ks = 0; ks < 4; ++ks)
        a4[ks] = *(const f16x8*)(const void*)(wtp + c * NF + ks * 32 + 8 * g);
    #pragma unroll
    for (int ks = 0; ks < 4; ++ks) {
        #pragma unroll
        for (int nf = 0; nf < 4; ++nf) {
            if (nf >= ntile) continue;   // block-uniform branch
            const int row = nf * 16 + c;
            f16x8 bfr = *(const f16x8*)(X + row * 256 + ((ks * 64 + 16 * g) ^ ((row & 7) << 4)));
            acc[nf] = __builtin_amdgcn_mfma_f32_16x16x32_f16(a4[ks], bfr, acc[nf], 0, 0, 0);
        }
    }
}

// Row mean/var of frag-resident h^T (lane: n = nf*16+c; 4 f-vals each).
// Includes two __syncthreads() (first one also orders prior LDS reads).
__device__ __forceinline__ void ln_stats(const f32x4 (&h)[4],
                                         float* __restrict__ part, float* __restrict__ part2,
                                         float* __restrict__ mu_s, float* __restrict__ rs_s,
                                         int t, int w, int c)
{
    #pragma unroll
    for (int nf = 0; nf < 4; ++nf) {
        float s  = h[nf][0] + h[nf][1] + h[nf][2] + h[nf][3];
        float s2 = h[nf][0]*h[nf][0] + h[nf][1]*h[nf][1] + h[nf][2]*h[nf][2] + h[nf][3]*h[nf][3];
        s  += __shfl_xor(s, 16);  s  += __shfl_xor(s, 32);
        s2 += __shfl_xor(s2, 16); s2 += __shfl_xor(s2, 32);
        if ((t & 63) < 16) { const int n = nf * 16 + c; part[n*9 + w] = s; part2[n*9 + w] = s2; }
    }
    __syncthreads();
    if (t < 64) {
        float s = 0.f, s2 = 0.f;
        #pragma unroll
        for (int q = 0; q < 8; ++q) { s += part[t*9 + q]; s2 += part2[t*9 + q]; }
        float mu = s * (1.f / 128.f);
        float var = s2 * (1.f / 128.f) - mu * mu;
        mu_s[t] = mu; rs_s[t] = rsqrtf(fmaxf(var, 0.f) + 1e-5f);
    }
    __syncthreads();
}

__device__ __forceinline__ void st_rows(char* __restrict__ B, const f32x4 (&acc)[4],
                                        int c, int g, int f0)
{
    #pragma unroll
    for (int nf = 0; nf < 4; ++nf) {
        const int n = nf * 16 + c;
        ushort4 o = make_ushort4(f2h(acc[nf][0]), f2h(acc[nf][1]),
                                 f2h(acc[nf][2]), f2h(acc[nf][3]));
        *(ushort4*)(B + n * 256 + ((2 * (f0 + 4 * g)) ^ ((n & 7) << 4))) = o;
    }
}

__device__ __forceinline__ void st_vt(char* __restrict__ VT_, const f32x4 (&acc)[4],
                                      int c, int g, int f0)
{
    #pragma unroll
    for (int nf = 0; nf < 4; ++nf) {
        #pragma unroll
        for (int r = 0; r < 4; ++r) {
            const int fr = f0 + 4 * g + r;
            *(unsigned short*)(VT_ + fr * 128 + ((2 * (nf * 16 + c)) ^ ((fr & 7) << 4)))
                = f2h(acc[nf][r]);
        }
    }
}

template<bool BF16>
__global__ __launch_bounds__(NTH)
__attribute__((amdgpu_waves_per_eu(4, 4)))
void gnn_mfma(const void* __restrict__ coords,
              const int*  __restrict__ species,
              const unsigned char* __restrict__ maskraw,
              const void* __restrict__ embed,
              const void* __restrict__ Wq,      // dtype-detect only
              const void* __restrict__ We,
              const void* __restrict__ bfb,
              void* __restrict__ out)
{
    if (detect_bf16(Wq) != BF16) return;   // block-uniform early exit

    extern __shared__ char smem2[];
    char* HN = smem2;                 // [64][128] f16 swz : hn, then msg
    char* QB = HN + 16384;            // [64][128] f16 swz : q, then P
    char* KB = QB + 16384;            // [64][128] f16 swz : k
    char* VT = KB + 16384;            // [128][64] f16 swz : v^T (f-major)
    float* cs    = (float*)(VT + 16384);   // 64*4
    float* wel   = cs + 256;               // 48
    float* mu_s  = wel + 48;               // 64
    float* rs_s  = mu_s + 64;              // 64
    float* part  = rs_s + 64;              // 64*9
    float* part2 = part + 576;             // 64*9
    int*   lenp  = (int*)(part2 + 576);

    const int t = threadIdx.x, b = blockIdx.x;
    const int w = t >> 6, la = t & 63, g = la >> 4, c = la & 15;
    const int f0 = w * 16;
    const f32x4 z4 = {0.f, 0.f, 0.f, 0.f};

    if (t < 64) {
        cs[t*4+0] = ldT<BF16>(coords, (b * NATOM + t) * 3 + 0);
        cs[t*4+1] = ldT<BF16>(coords, (b * NATOM + t) * 3 + 1);
        cs[t*4+2] = ldT<BF16>(coords, (b * NATOM + t) * 3 + 2);
    }
    if (t >= 64 && t < 64 + 42) wel[t - 64] = ldT<BF16>(We, t - 64);
    if (t < 64) {
        unsigned int w0 = *(const unsigned int*)maskraw;
        bool fm;
        if (w0 == 1u)               fm = ((const int*)maskraw)[b * NATOM + t] != 0;
        else if (w0 == 0x01010101u) fm = maskraw[b * NATOM + t] != 0;
        else if (w0 == 0x3F800000u) fm = ((const float*)maskraw)[b * NATOM + t] != 0.f;
        else                        fm = ((const unsigned short*)maskraw)[b * NATOM + t] != 0;
        unsigned long long bal = __ballot(fm);
        if (t == 0) *lenp = (int)__popcll(bal);
    }

    // h^T resident in C-frag layout: hst[nf][r] = h[n = nf*16+c][f = f0+4g+r]
    f32x4 hst[4];
    #pragma unroll
    for (int nf = 0; nf < 4; ++nf) {
        const int n = nf * 16 + c;
        const int sp = species[b * NATOM + n];
        float4 ev = ld4T<BF16>(embed, (sp - 1) * NF + f0 + 4 * g);
        hst[nf][0] = ev.x; hst[nf][1] = ev.y; hst[nf][2] = ev.z; hst[nf][3] = ev.w;
    }
    __syncthreads();
    const int len = *lenp;
    const int ntile = (len + 15) >> 4;    // block-uniform active 16-row tiles
    #pragma unroll
    for (int nf = 0; nf < 4; ++nf)
        if (nf * 16 + c >= len) hst[nf] = z4;

    const int hd = w >> 2;            // attention: wave -> (head, n-stripe)
    const int n0 = (w & 3) * 16;
    const bool wactive = (n0 < len);  // wave-uniform: this n-stripe has live rows

    for (int ly = 0; ly < NLAYER; ++ly) {
        const unsigned short* wqT = g_wt + (0 * 3 + ly) * 16384;
        const unsigned short* wkT = g_wt + (1 * 3 + ly) * 16384;
        const unsigned short* wvT = g_wt + (2 * 3 + ly) * 16384;
        const unsigned short* woT = g_wt + (3 * 3 + ly) * 16384;
        const unsigned short* wfT = g_wt + (4 * 3 + ly) * 16384;

        // ---- LN1 -> HN (f16, swizzled) ----
        ln_stats(hst, part, part2, mu_s, rs_s, t, w, c);
        #pragma unroll
        for (int nf = 0; nf < 4; ++nf) {
            const int n = nf * 16 + c;
            const float mu = mu_s[n], rs = rs_s[n];
            ushort4 o = make_ushort4(f2h((hst[nf][0]-mu)*rs), f2h((hst[nf][1]-mu)*rs),
                                     f2h((hst[nf][2]-mu)*rs), f2h((hst[nf][3]-mu)*rs));
            *(ushort4*)(HN + n * 256 + ((2 * (f0 + 4 * g)) ^ ((n & 7) << 4))) = o;
        }
        __syncthreads();

        // ---- q,k,v = LN(h) @ W{q,k,v} ----
        {
            f32x4 acc[4] = {z4, z4, z4, z4};
            mm_t(wqT + f0 * NF, HN, acc, c, g, ntile);
            st_rows(QB, acc, c, g, f0);
            acc[0]=z4; acc[1]=z4; acc[2]=z4; acc[3]=z4;
            mm_t(wkT + f0 * NF, HN, acc, c, g, ntile);
            st_rows(KB, acc, c, g, f0);
            acc[0]=z4; acc[1]=z4; acc[2]=z4; acc[3]=z4;
            mm_t(wvT + f0 * NF, HN, acc, c, g, ntile);
            st_vt(VT, acc, c, g, f0);
        }
        __syncthreads();

        // ---- swapped QK^T: sacc[mf] = S^T[m][n], m = mf*16+4g+r, n = n0+c ----
        f32x4 sacc[4] = {z4, z4, z4, z4};
        if (wactive) {
            #pragma unroll
            for (int ks = 0; ks < 2; ++ks) {
                const int bc = hd * 128 + ks * 64 + 16 * g;
                const int qrow = n0 + c;
                f16x8 bq = *(const f16x8*)(QB + qrow * 256 + (bc ^ ((qrow & 7) << 4)));
                #pragma unroll
                for (int mf = 0; mf < 4; ++mf) {
                    if (mf >= ntile) continue;
                    const int krow = mf * 16 + c;
                    f16x8 ak = *(const f16x8*)(KB + krow * 256 + (bc ^ ((krow & 7) << 4)));
                    sacc[mf] = __builtin_amdgcn_mfma_f32_16x16x32_f16(ak, bq, sacc[mf], 0, 0, 0);
                }
            }
            // edges + masked softmax over m (lanes sharing n: xor 16, 32)
            float we_[7];
            #pragma unroll
            for (int e = 0; e < 7; ++e) we_[e] = wel[ly * 14 + e * 2 + hd];
            const float cnx = cs[(n0+c)*4+0], cny = cs[(n0+c)*4+1], cnz = cs[(n0+c)*4+2];
            float mx = -1e30f;
            #pragma unroll
            for (int mf = 0; mf < 4; ++mf) {
                if (mf < ntile) {
                    #pragma unroll
                    for (int r = 0; r < 4; ++r) {
                        const int m = mf * 16 + 4 * g + r;
                        float dx = cnx - cs[m*4+0];
                        float dy = cny - cs[m*4+1];
                        float dz = cnz - cs[m*4+2];
                        float d  = fsqrt_(dx*dx + dy*dy + dz*dz + 1e-12f);
                        float et = __expf(-d);
                        float s1 = frcp(1.f + 7.38905609893065f   * et);  // sigmoid(d-2)
                        float s2 = frcp(1.f + 54.598150033144236f * et);  // sigmoid(d-4)
                        float s3 = frcp(1.f + 403.4287934927351f  * et);  // sigmoid(d-6)
                        float val = sacc[mf][r] * 0.125f
                                  + dx*we_[0] + dy*we_[1] + dz*we_[2] + d*we_[3]
                                  + s1*we_[4] + s2*we_[5] + s3*we_[6];
                        if (m >= len) val = -1e30f;
                        sacc[mf][r] = val;
                        mx = fmaxf(mx, val);
                    }
                } else {
                    sacc[mf] = (f32x4){-1e30f, -1e30f, -1e30f, -1e30f};
                }
            }
            mx = fmaxf(mx, __shfl_xor(mx, 16));
            mx = fmaxf(mx, __shfl_xor(mx, 32));
            float sm = 0.f;
            #pragma unroll
            for (int mf = 0; mf < 4; ++mf) {
                if (mf < ntile) {
                    #pragma unroll
                    for (int r = 0; r < 4; ++r) {
                        float e = __expf(sacc[mf][r] - mx);
                        sacc[mf][r] = e; sm += e;
                    }
                } else {
                    sacc[mf] = z4;   // masked tiles: zero probability
                }
            }
            sm += __shfl_xor(sm, 16);
            sm += __shfl_xor(sm, 32);
            const float inv = frcp(sm);        // >= 1 valid entry per live row
            #pragma unroll
            for (int mf = 0; mf < 4; ++mf) {
                sacc[mf][0] *= inv; sacc[mf][1] *= inv;
                sacc[mf][2] *= inv; sacc[mf][3] *= inv;
            }
        }
        __syncthreads();                       // all q/k reads complete
        if (wactive) {
            #pragma unroll
            for (int mf = 0; mf < 4; ++mf) {   // P[n][m] f16 into QB
                const int prow = n0 + c;
                ushort4 o = make_ushort4(f2h(sacc[mf][0]), f2h(sacc[mf][1]),
                                         f2h(sacc[mf][2]), f2h(sacc[mf][3]));
                *(ushort4*)(QB + prow * 256 + ((hd * 128 + mf * 32 + 8 * g) ^ ((prow & 7) << 4))) = o;
            }
        }
        __syncthreads();

        // ---- PV: msg^T = V^T * P^T ; msg[n][f] into HN ----
        {
            const int d0 = (w & 3) * 16;
            f32x4 macc[4] = {z4, z4, z4, z4};
            #pragma unroll
            for (int ks = 0; ks < 2; ++ks) {
                if (ks * 32 >= len) continue;          // m-slice fully masked
                const int vrow = hd * 64 + d0 + c;
                f16x8 av = *(const f16x8*)(VT + vrow * 128 + ((ks * 64 + 16 * g) ^ ((vrow & 7) << 4)));
                #pragma unroll
                for (int nf = 0; nf < 4; ++nf) {
                    if (nf >= ntile) continue;
                    const int prow = nf * 16 + c;
                    f16x8 bp = *(const f16x8*)(QB + prow * 256 +
                                 ((hd * 128 + ks * 64 + 16 * g) ^ ((prow & 7) << 4)));
                    macc[nf] = __builtin_amdgcn_mfma_f32_16x16x32_f16(av, bp, macc[nf], 0, 0, 0);
                }
            }
            #pragma unroll
            for (int nf = 0; nf < 4; ++nf) {
                const int n = nf * 16 + c;
                ushort4 o = make_ushort4(f2h(macc[nf][0]), f2h(macc[nf][1]),
                                         f2h(macc[nf][2]), f2h(macc[nf][3]));
                *(ushort4*)(HN + n * 256 + ((hd * 128 + (w & 3) * 32 + 8 * g) ^ ((n & 7) << 4))) = o;
            }
        }
        __syncthreads();

        // ---- h += msg @ Wo ----
        {
            f32x4 acc[4] = {z4, z4, z4, z4};
            mm_t(woT + f0 * NF, HN, acc, c, g, ntile);
            #pragma unroll
            for (int nf = 0; nf < 4; ++nf) hst[nf] += acc[nf];
        }
        // ---- LN2 -> HN (ln_stats' first barrier orders all Wo reads first) ----
        ln_stats(hst, part, part2, mu_s, rs_s, t, w, c);
        #pragma unroll
        for (int nf = 0; nf < 4; ++nf) {
            const int n = nf * 16 + c;
            const float mu = mu_s[n], rs = rs_s[n];
            ushort4 o = make_ushort4(f2h((hst[nf][0]-mu)*rs), f2h((hst[nf][1]-mu)*rs),
                                     f2h((hst[nf][2]-mu)*rs), f2h((hst[nf][3]-mu)*rs));
            *(ushort4*)(HN + n * 256 + ((2 * (f0 + 4 * g)) ^ ((n & 7) << 4))) = o;
        }
        __syncthreads();
        // ---- h += tanh(LN2(h) @ Wf + bf) ----
        {
            f32x4 acc[4] = {z4, z4, z4, z4};
            mm_t(wfT + f0 * NF, HN, acc, c, g, ntile);
            float4 bv = ld4T<BF16>(bfb, ly * NF + f0 + 4 * g);
            #pragma unroll
            for (int nf = 0; nf < 4; ++nf) {
                if (nf >= ntile) continue;     // masked rows stay zero
                hst[nf][0] += ftanh(acc[nf][0] + bv.x);
                hst[nf][1] += ftanh(acc[nf][1] + bv.y);
                hst[nf][2] += ftanh(acc[nf][2] + bv.z);
                hst[nf][3] += ftanh(acc[nf][3] + bv.w);
            }
        }
        #pragma unroll
        for (int nf = 0; nf < 4; ++nf)
            if (nf * 16 + c >= len) hst[nf] = z4;
        // next iteration's ln_stats barrier orders Wf reads vs HN rewrite
    }

    // ---- out = LN(h), in the input dtype (nontemporal: don't pollute L2) ----
    ln_stats(hst, part, part2, mu_s, rs_s, t, w, c);
    #pragma unroll
    for (int nf = 0; nf < 4; ++nf) {
        const int n = nf * 16 + c;
        const float mu = mu_s[n], rs = rs_s[n];
        const int idx = (b * NATOM + n) * NF + f0 + 4 * g;
        if constexpr (BF16) {
            us4v o = { f2bf((hst[nf][0]-mu)*rs), f2bf((hst[nf][1]-mu)*rs),
                       f2bf((hst[nf][2]-mu)*rs), f2bf((hst[nf][3]-mu)*rs) };
            __builtin_nontemporal_store(o, (us4v*)((unsigned short*)out + idx));
        } else {
            f32x4 o = { (hst[nf][0]-mu)*rs, (hst[nf][1]-mu)*rs,
                        (hst[nf][2]-mu)*rs, (hst[nf][3]-mu)*rs };
            __builtin_nontemporal_store(o, (f32x4*)((float*)out + idx));
        }
    }
}

static constexpr size_t SMEM2_BYTES =
    4 * 16384 + (256 + 48 + 64 + 64 + 576 + 576 + 4) * sizeof(float);   // 71888

extern "C" void kernel_launch(void* const* d_in, const int* in_sizes, int n_in,
                              void* d_out, int out_size, void* d_ws, size_t ws_size,
                              hipStream_t stream) {
    const void*           coords  = d_in[0];
    const int*            species = (const int*)d_in[1];
    const unsigned char*  maskraw = (const unsigned char*)d_in[2];
    const void*           embed   = d_in[3];
    const void*           Wq      = d_in[4];
    const void*           Wk      = d_in[5];
    const void*           Wv      = d_in[6];
    const void*           Wo      = d_in[7];
    const void*           We      = d_in[8];
    const void*           Wf      = d_in[9];
    const void*           bfb     = d_in[10];
    (void)d_ws; (void)ws_size; (void)in_sizes; (void)n_in; (void)out_size;

    (void)hipFuncSetAttribute((const void*)gnn_mfma<false>,
                              hipFuncAttributeMaxDynamicSharedMemorySize,
                              (int)SMEM2_BYTES);
    (void)hipFuncSetAttribute((const void*)gnn_mfma<true>,
                              hipFuncAttributeMaxDynamicSharedMemorySize,
                              (int)SMEM2_BYTES);

    transpose_w<<<dim3(15), dim3(256), 0, stream>>>(Wq, Wk, Wv, Wo, Wf);
    gnn_mfma<false><<<dim3(NBATCH), dim3(NTH), SMEM2_BYTES, stream>>>(
        coords, species, maskraw, embed, Wq, We, bfb, d_out);
    gnn_mfma<true><<<dim3(NBATCH), dim3(NTH), SMEM2_BYTES, stream>>>(
        coords, species, maskraw, embed, Wq, We, bfb, d_out);
}

// Round 6
// 463.223 us; speedup vs baseline: 1.3874x; 1.1158x over previous
//
#include <hip/hip_runtime.h>

// NucleiGNN fused forward: B=2048 molecules, one block (512 thr) per molecule.
// All matmuls on v_mfma_f32_16x16x32_f16 with f32 accumulation; h resident in
// C-fragment registers (transposed orientation). Weights pre-transposed +
// f16-converted into a static __device__ array. XOR-swizzled f16 LDS tiles,
// ~70KB LDS -> 2 blocks/CU.
// Round-6: kill the scratch spill for real. rocprof: VGPR=64 persisted and
// FETCH/WRITE ~450/490MB symmetric (=~400B/thread spill traffic). The
// amdgpu_waves_per_eu attribute was overridden by __launch_bounds__; use
// __launch_bounds__(512, 2) instead (2nd arg = MIN WAVES PER EU) -> VGPR
// budget up to ~256. Occupancy stays LDS-capped at 4 waves/EU regardless.

#define NBATCH 2048
#define NATOM  64
#define NF     128
#define NLAYER 3
#define NTH    512

typedef __attribute__((ext_vector_type(8))) _Float16 f16x8;
typedef __attribute__((ext_vector_type(4))) float    f32x4;
typedef __attribute__((ext_vector_type(4))) unsigned short us4v;

// WT[f][k] as f16 bits: 15 matrices (Wq,Wk,Wv,Wo,Wf) x 3 layers, 128x128 each.
__device__ __align__(16) unsigned short g_wt[15 * NF * NF];

__device__ __forceinline__ float bf2f(unsigned short u) {
    union { unsigned int i; float f; } v; v.i = ((unsigned int)u) << 16; return v.f;
}
__device__ __forceinline__ unsigned short f2bf(float f) {
    union { float ff; unsigned int i; } v; v.ff = f;
    unsigned int x = v.i;
    if ((x & 0x7f800000u) == 0x7f800000u) return (unsigned short)(x >> 16);
    return (unsigned short)((x + 0x7fffu + ((x >> 16) & 1u)) >> 16);
}
__device__ __forceinline__ unsigned short f2h(float f) {
    union { _Float16 h; unsigned short u; } v; v.h = (_Float16)f; return v.u;
}
__device__ __forceinline__ float frcp(float x) { return __builtin_amdgcn_rcpf(x); }
__device__ __forceinline__ float fsqrt_(float x) { return __builtin_amdgcn_sqrtf(x); }
__device__ __forceinline__ float ftanh(float x) {
    // tanh(x) = 1 - 2/(exp(2x)+1); exp overflow/underflow saturates correctly
    return 1.f - 2.f * frcp(__expf(2.f * x) + 1.f);
}

template<bool BF16>
__device__ __forceinline__ float ldT(const void* p, int i) {
    if constexpr (BF16) return bf2f(((const unsigned short*)p)[i]);
    else                return ((const float*)p)[i];
}
template<bool BF16>
__device__ __forceinline__ float4 ld4T(const void* p, int i) {
    if constexpr (BF16) {
        ushort4 v = *(const ushort4*)((const unsigned short*)p + i);
        return make_float4(bf2f(v.x), bf2f(v.y), bf2f(v.z), bf2f(v.w));
    } else {
        return *(const float4*)((const float*)p + i);
    }
}

__device__ __forceinline__ bool detect_bf16(const void* Wq) {
    const unsigned int* w = (const unsigned int*)Wq;
    bool isbf = true;
    #pragma unroll
    for (int i = 0; i < 16; ++i) {
        unsigned int e = (w[i] >> 7) & 0xFFu;   // low-bf16 exponent if bf16-packed
        isbf = isbf && (e >= 0x60u && e <= 0x7Eu);
    }
    return isbf;
}

// ---- weight transpose + f16 convert: WT[f][k] = (f16)W[k][f] into g_wt ----
__global__ __launch_bounds__(256)
void transpose_w(const void* Wq_, const void* Wk_, const void* Wv_,
                 const void* Wo_, const void* Wf_)
{
    const bool isbf = detect_bf16(Wq_);
    __shared__ unsigned short tile[128 * 136];
    const int m = blockIdx.x, a = m / 3, ly = m % 3, t = threadIdx.x;
    const void* src = (a == 0 ? Wq_ : a == 1 ? Wk_ : a == 2 ? Wv_ : a == 3 ? Wo_ : Wf_);
    unsigned short* dst = g_wt + m * 16384;
    #pragma unroll
    for (int i = 0; i < 16; ++i) {
        int e = (i * 256 + t) * 4;          // elements e..e+3 = row r, cols c0..c0+3
        int r = e >> 7, c0 = e & 127;
        float4 v;
        if (isbf) {
            ushort4 u = *(const ushort4*)((const unsigned short*)src + ly * 16384 + e);
            v = make_float4(bf2f(u.x), bf2f(u.y), bf2f(u.z), bf2f(u.w));
        } else {
            v = *(const float4*)((const float*)src + ly * 16384 + e);
        }
        tile[(c0+0)*136 + r] = f2h(v.x); tile[(c0+1)*136 + r] = f2h(v.y);
        tile[(c0+2)*136 + r] = f2h(v.z); tile[(c0+3)*136 + r] = f2h(v.w);
    }
    __syncthreads();
    #pragma unroll
    for (int i = 0; i < 16; ++i) {
        int e = (i * 256 + t) * 4;
        int f = e >> 7, k0 = e & 127;
        *(ushort4*)(dst + e) = *(const ushort4*)&tile[f * 136 + k0];
    }
}

// Y^T = W^T * X^T for one 16-row f-stripe per wave, 4 n-frags (tiles >= ntile
// are fully masked -> skipped; their acc stays 0 and gets stored as zeros).
// A-frag: WT rows (global, 16B); B-frag: X rows in swizzled f16 LDS (16B).
__device__ __forceinline__ void mm_t(const unsigned short* __restrict__ wtp,
                                     const char* __restrict__ X,
                                     f32x4 (&acc)[4], int c, int g, int ntile)
{
    f16x8 a4[4];
    #pragma unroll
    for (int ks = 0; ks < 4; ++ks)
        a4[ks] = *(const f16x8*)(const void*)(wtp + c * NF + ks * 32 + 8 * g);
    #pragma unroll
    for (int ks = 0; ks < 4; ++ks) {
        #pragma unroll
        for (int nf = 0; nf < 4; ++nf) {
            if (nf >= ntile) continue;   // block-uniform branch
            const int row = nf * 16 + c;
            f16x8 bfr = *(const f16x8*)(X + row * 256 + ((ks * 64 + 16 * g) ^ ((row & 7) << 4)));
            acc[nf] = __builtin_amdgcn_mfma_f32_16x16x32_f16(a4[ks], bfr, acc[nf], 0, 0, 0);
        }
    }
}

// Row mean/var of frag-resident h^T (lane: n = nf*16+c; 4 f-vals each).
// Includes two __syncthreads() (first one also orders prior LDS reads).
__device__ __forceinline__ void ln_stats(const f32x4 (&h)[4],
                                         float* __restrict__ part, float* __restrict__ part2,
                                         float* __restrict__ mu_s, float* __restrict__ rs_s,
                                         int t, int w, int c)
{
    #pragma unroll
    for (int nf = 0; nf < 4; ++nf) {
        float s  = h[nf][0] + h[nf][1] + h[nf][2] + h[nf][3];
        float s2 = h[nf][0]*h[nf][0] + h[nf][1]*h[nf][1] + h[nf][2]*h[nf][2] + h[nf][3]*h[nf][3];
        s  += __shfl_xor(s, 16);  s  += __shfl_xor(s, 32);
        s2 += __shfl_xor(s2, 16); s2 += __shfl_xor(s2, 32);
        if ((t & 63) < 16) { const int n = nf * 16 + c; part[n*9 + w] = s; part2[n*9 + w] = s2; }
    }
    __syncthreads();
    if (t < 64) {
        float s = 0.f, s2 = 0.f;
        #pragma unroll
        for (int q = 0; q < 8; ++q) { s += part[t*9 + q]; s2 += part2[t*9 + q]; }
        float mu = s * (1.f / 128.f);
        float var = s2 * (1.f / 128.f) - mu * mu;
        mu_s[t] = mu; rs_s[t] = rsqrtf(fmaxf(var, 0.f) + 1e-5f);
    }
    __syncthreads();
}

__device__ __forceinline__ void st_rows(char* __restrict__ B, const f32x4 (&acc)[4],
                                        int c, int g, int f0)
{
    #pragma unroll
    for (int nf = 0; nf < 4; ++nf) {
        const int n = nf * 16 + c;
        ushort4 o = make_ushort4(f2h(acc[nf][0]), f2h(acc[nf][1]),
                                 f2h(acc[nf][2]), f2h(acc[nf][3]));
        *(ushort4*)(B + n * 256 + ((2 * (f0 + 4 * g)) ^ ((n & 7) << 4))) = o;
    }
}

__device__ __forceinline__ void st_vt(char* __restrict__ VT_, const f32x4 (&acc)[4],
                                      int c, int g, int f0)
{
    #pragma unroll
    for (int nf = 0; nf < 4; ++nf) {
        #pragma unroll
        for (int r = 0; r < 4; ++r) {
            const int fr = f0 + 4 * g + r;
            *(unsigned short*)(VT_ + fr * 128 + ((2 * (nf * 16 + c)) ^ ((fr & 7) << 4)))
                = f2h(acc[nf][r]);
        }
    }
}

template<bool BF16>
__global__ __launch_bounds__(NTH, 2)   // min 2 waves/EU -> VGPR budget ~256; LDS caps real occupancy at 4 waves/EU
void gnn_mfma(const void* __restrict__ coords,
              const int*  __restrict__ species,
              const unsigned char* __restrict__ maskraw,
              const void* __restrict__ embed,
              const void* __restrict__ Wq,      // dtype-detect only
              const void* __restrict__ We,
              const void* __restrict__ bfb,
              void* __restrict__ out)
{
    if (detect_bf16(Wq) != BF16) return;   // block-uniform early exit

    extern __shared__ char smem2[];
    char* HN = smem2;                 // [64][128] f16 swz : hn, then msg
    char* QB = HN + 16384;            // [64][128] f16 swz : q, then P
    char* KB = QB + 16384;            // [64][128] f16 swz : k
    char* VT = KB + 16384;            // [128][64] f16 swz : v^T (f-major)
    float* cs    = (float*)(VT + 16384);   // 64*4
    float* wel   = cs + 256;               // 48
    float* mu_s  = wel + 48;               // 64
    float* rs_s  = mu_s + 64;              // 64
    float* part  = rs_s + 64;              // 64*9
    float* part2 = part + 576;             // 64*9
    int*   lenp  = (int*)(part2 + 576);

    const int t = threadIdx.x, b = blockIdx.x;
    const int w = t >> 6, la = t & 63, g = la >> 4, c = la & 15;
    const int f0 = w * 16;
    const f32x4 z4 = {0.f, 0.f, 0.f, 0.f};

    if (t < 64) {
        cs[t*4+0] = ldT<BF16>(coords, (b * NATOM + t) * 3 + 0);
        cs[t*4+1] = ldT<BF16>(coords, (b * NATOM + t) * 3 + 1);
        cs[t*4+2] = ldT<BF16>(coords, (b * NATOM + t) * 3 + 2);
    }
    if (t >= 64 && t < 64 + 42) wel[t - 64] = ldT<BF16>(We, t - 64);
    if (t < 64) {
        unsigned int w0 = *(const unsigned int*)maskraw;
        bool fm;
        if (w0 == 1u)               fm = ((const int*)maskraw)[b * NATOM + t] != 0;
        else if (w0 == 0x01010101u) fm = maskraw[b * NATOM + t] != 0;
        else if (w0 == 0x3F800000u) fm = ((const float*)maskraw)[b * NATOM + t] != 0.f;
        else                        fm = ((const unsigned short*)maskraw)[b * NATOM + t] != 0;
        unsigned long long bal = __ballot(fm);
        if (t == 0) *lenp = (int)__popcll(bal);
    }

    // h^T resident in C-frag layout: hst[nf][r] = h[n = nf*16+c][f = f0+4g+r]
    f32x4 hst[4];
    #pragma unroll
    for (int nf = 0; nf < 4; ++nf) {
        const int n = nf * 16 + c;
        const int sp = species[b * NATOM + n];
        float4 ev = ld4T<BF16>(embed, (sp - 1) * NF + f0 + 4 * g);
        hst[nf][0] = ev.x; hst[nf][1] = ev.y; hst[nf][2] = ev.z; hst[nf][3] = ev.w;
    }
    __syncthreads();
    const int len = *lenp;
    const int ntile = (len + 15) >> 4;    // block-uniform active 16-row tiles
    #pragma unroll
    for (int nf = 0; nf < 4; ++nf)
        if (nf * 16 + c >= len) hst[nf] = z4;

    const int hd = w >> 2;            // attention: wave -> (head, n-stripe)
    const int n0 = (w & 3) * 16;
    const bool wactive = (n0 < len);  // wave-uniform: this n-stripe has live rows

    for (int ly = 0; ly < NLAYER; ++ly) {
        const unsigned short* wqT = g_wt + (0 * 3 + ly) * 16384;
        const unsigned short* wkT = g_wt + (1 * 3 + ly) * 16384;
        const unsigned short* wvT = g_wt + (2 * 3 + ly) * 16384;
        const unsigned short* woT = g_wt + (3 * 3 + ly) * 16384;
        const unsigned short* wfT = g_wt + (4 * 3 + ly) * 16384;

        // ---- LN1 -> HN (f16, swizzled) ----
        ln_stats(hst, part, part2, mu_s, rs_s, t, w, c);
        #pragma unroll
        for (int nf = 0; nf < 4; ++nf) {
            const int n = nf * 16 + c;
            const float mu = mu_s[n], rs = rs_s[n];
            ushort4 o = make_ushort4(f2h((hst[nf][0]-mu)*rs), f2h((hst[nf][1]-mu)*rs),
                                     f2h((hst[nf][2]-mu)*rs), f2h((hst[nf][3]-mu)*rs));
            *(ushort4*)(HN + n * 256 + ((2 * (f0 + 4 * g)) ^ ((n & 7) << 4))) = o;
        }
        __syncthreads();

        // ---- q,k,v = LN(h) @ W{q,k,v} ----
        {
            f32x4 acc[4] = {z4, z4, z4, z4};
            mm_t(wqT + f0 * NF, HN, acc, c, g, ntile);
            st_rows(QB, acc, c, g, f0);
            acc[0]=z4; acc[1]=z4; acc[2]=z4; acc[3]=z4;
            mm_t(wkT + f0 * NF, HN, acc, c, g, ntile);
            st_rows(KB, acc, c, g, f0);
            acc[0]=z4; acc[1]=z4; acc[2]=z4; acc[3]=z4;
            mm_t(wvT + f0 * NF, HN, acc, c, g, ntile);
            st_vt(VT, acc, c, g, f0);
        }
        __syncthreads();

        // ---- swapped QK^T: sacc[mf] = S^T[m][n], m = mf*16+4g+r, n = n0+c ----
        f32x4 sacc[4] = {z4, z4, z4, z4};
        if (wactive) {
            #pragma unroll
            for (int ks = 0; ks < 2; ++ks) {
                const int bc = hd * 128 + ks * 64 + 16 * g;
                const int qrow = n0 + c;
                f16x8 bq = *(const f16x8*)(QB + qrow * 256 + (bc ^ ((qrow & 7) << 4)));
                #pragma unroll
                for (int mf = 0; mf < 4; ++mf) {
                    if (mf >= ntile) continue;
                    const int krow = mf * 16 + c;
                    f16x8 ak = *(const f16x8*)(KB + krow * 256 + (bc ^ ((krow & 7) << 4)));
                    sacc[mf] = __builtin_amdgcn_mfma_f32_16x16x32_f16(ak, bq, sacc[mf], 0, 0, 0);
                }
            }
            // edges + masked softmax over m (lanes sharing n: xor 16, 32)
            float we_[7];
            #pragma unroll
            for (int e = 0; e < 7; ++e) we_[e] = wel[ly * 14 + e * 2 + hd];
            const float cnx = cs[(n0+c)*4+0], cny = cs[(n0+c)*4+1], cnz = cs[(n0+c)*4+2];
            float mx = -1e30f;
            #pragma unroll
            for (int mf = 0; mf < 4; ++mf) {
                if (mf < ntile) {
                    #pragma unroll
                    for (int r = 0; r < 4; ++r) {
                        const int m = mf * 16 + 4 * g + r;
                        float dx = cnx - cs[m*4+0];
                        float dy = cny - cs[m*4+1];
                        float dz = cnz - cs[m*4+2];
                        float d  = fsqrt_(dx*dx + dy*dy + dz*dz + 1e-12f);
                        float et = __expf(-d);
                        float s1 = frcp(1.f + 7.38905609893065f   * et);  // sigmoid(d-2)
                        float s2 = frcp(1.f + 54.598150033144236f * et);  // sigmoid(d-4)
                        float s3 = frcp(1.f + 403.4287934927351f  * et);  // sigmoid(d-6)
                        float val = sacc[mf][r] * 0.125f
                                  + dx*we_[0] + dy*we_[1] + dz*we_[2] + d*we_[3]
                                  + s1*we_[4] + s2*we_[5] + s3*we_[6];
                        if (m >= len) val = -1e30f;
                        sacc[mf][r] = val;
                        mx = fmaxf(mx, val);
                    }
                } else {
                    sacc[mf] = (f32x4){-1e30f, -1e30f, -1e30f, -1e30f};
                }
            }
            mx = fmaxf(mx, __shfl_xor(mx, 16));
            mx = fmaxf(mx, __shfl_xor(mx, 32));
            float sm = 0.f;
            #pragma unroll
            for (int mf = 0; mf < 4; ++mf) {
                if (mf < ntile) {
                    #pragma unroll
                    for (int r = 0; r < 4; ++r) {
                        float e = __expf(sacc[mf][r] - mx);
                        sacc[mf][r] = e; sm += e;
                    }
                } else {
                    sacc[mf] = z4;   // masked tiles: zero probability
                }
            }
            sm += __shfl_xor(sm, 16);
            sm += __shfl_xor(sm, 32);
            const float inv = frcp(sm);        // >= 1 valid entry per live row
            #pragma unroll
            for (int mf = 0; mf < 4; ++mf) {
                sacc[mf][0] *= inv; sacc[mf][1] *= inv;
                sacc[mf][2] *= inv; sacc[mf][3] *= inv;
            }
        }
        __syncthreads();                       // all q/k reads complete
        if (wactive) {
            #pragma unroll
            for (int mf = 0; mf < 4; ++mf) {   // P[n][m] f16 into QB
                const int prow = n0 + c;
                ushort4 o = make_ushort4(f2h(sacc[mf][0]), f2h(sacc[mf][1]),
                                         f2h(sacc[mf][2]), f2h(sacc[mf][3]));
                *(ushort4*)(QB + prow * 256 + ((hd * 128 + mf * 32 + 8 * g) ^ ((prow & 7) << 4))) = o;
            }
        }
        __syncthreads();

        // ---- PV: msg^T = V^T * P^T ; msg[n][f] into HN ----
        {
            const int d0 = (w & 3) * 16;
            f32x4 macc[4] = {z4, z4, z4, z4};
            #pragma unroll
            for (int ks = 0; ks < 2; ++ks) {
                if (ks * 32 >= len) continue;          // m-slice fully masked
                const int vrow = hd * 64 + d0 + c;
                f16x8 av = *(const f16x8*)(VT + vrow * 128 + ((ks * 64 + 16 * g) ^ ((vrow & 7) << 4)));
                #pragma unroll
                for (int nf = 0; nf < 4; ++nf) {
                    if (nf >= ntile) continue;
                    const int prow = nf * 16 + c;
                    f16x8 bp = *(const f16x8*)(QB + prow * 256 +
                                 ((hd * 128 + ks * 64 + 16 * g) ^ ((prow & 7) << 4)));
                    macc[nf] = __builtin_amdgcn_mfma_f32_16x16x32_f16(av, bp, macc[nf], 0, 0, 0);
                }
            }
            #pragma unroll
            for (int nf = 0; nf < 4; ++nf) {
                const int n = nf * 16 + c;
                ushort4 o = make_ushort4(f2h(macc[nf][0]), f2h(macc[nf][1]),
                                         f2h(macc[nf][2]), f2h(macc[nf][3]));
                *(ushort4*)(HN + n * 256 + ((hd * 128 + (w & 3) * 32 + 8 * g) ^ ((n & 7) << 4))) = o;
            }
        }
        __syncthreads();

        // ---- h += msg @ Wo ----
        {
            f32x4 acc[4] = {z4, z4, z4, z4};
            mm_t(woT + f0 * NF, HN, acc, c, g, ntile);
            #pragma unroll
            for (int nf = 0; nf < 4; ++nf) hst[nf] += acc[nf];
        }
        // ---- LN2 -> HN (ln_stats' first barrier orders all Wo reads first) ----
        ln_stats(hst, part, part2, mu_s, rs_s, t, w, c);
        #pragma unroll
        for (int nf = 0; nf < 4; ++nf) {
            const int n = nf * 16 + c;
            const float mu = mu_s[n], rs = rs_s[n];
            ushort4 o = make_ushort4(f2h((hst[nf][0]-mu)*rs), f2h((hst[nf][1]-mu)*rs),
                                     f2h((hst[nf][2]-mu)*rs), f2h((hst[nf][3]-mu)*rs));
            *(ushort4*)(HN + n * 256 + ((2 * (f0 + 4 * g)) ^ ((n & 7) << 4))) = o;
        }
        __syncthreads();
        // ---- h += tanh(LN2(h) @ Wf + bf) ----
        {
            f32x4 acc[4] = {z4, z4, z4, z4};
            mm_t(wfT + f0 * NF, HN, acc, c, g, ntile);
            float4 bv = ld4T<BF16>(bfb, ly * NF + f0 + 4 * g);
            #pragma unroll
            for (int nf = 0; nf < 4; ++nf) {
                if (nf >= ntile) continue;     // masked rows stay zero
                hst[nf][0] += ftanh(acc[nf][0] + bv.x);
                hst[nf][1] += ftanh(acc[nf][1] + bv.y);
                hst[nf][2] += ftanh(acc[nf][2] + bv.z);
                hst[nf][3] += ftanh(acc[nf][3] + bv.w);
            }
        }
        #pragma unroll
        for (int nf = 0; nf < 4; ++nf)
            if (nf * 16 + c >= len) hst[nf] = z4;
        // next iteration's ln_stats barrier orders Wf reads vs HN rewrite
    }

    // ---- out = LN(h), in the input dtype (nontemporal: don't pollute L2) ----
    ln_stats(hst, part, part2, mu_s, rs_s, t, w, c);
    #pragma unroll
    for (int nf = 0; nf < 4; ++nf) {
        const int n = nf * 16 + c;
        const float mu = mu_s[n], rs = rs_s[n];
        const int idx = (b * NATOM + n) * NF + f0 + 4 * g;
        if constexpr (BF16) {
            us4v o = { f2bf((hst[nf][0]-mu)*rs), f2bf((hst[nf][1]-mu)*rs),
                       f2bf((hst[nf][2]-mu)*rs), f2bf((hst[nf][3]-mu)*rs) };
            __builtin_nontemporal_store(o, (us4v*)((unsigned short*)out + idx));
        } else {
            f32x4 o = { (hst[nf][0]-mu)*rs, (hst[nf][1]-mu)*rs,
                        (hst[nf][2]-mu)*rs, (hst[nf][3]-mu)*rs };
            __builtin_nontemporal_store(o, (f32x4*)((float*)out + idx));
        }
    }
}

static constexpr size_t SMEM2_BYTES =
    4 * 16384 + (256 + 48 + 64 + 64 + 576 + 576 + 4) * sizeof(float);   // 71888

extern "C" void kernel_launch(void* const* d_in, const int* in_sizes, int n_in,
                              void* d_out, int out_size, void* d_ws, size_t ws_size,
                              hipStream_t stream) {
    const void*           coords  = d_in[0];
    const int*            species = (const int*)d_in[1];
    const unsigned char*  maskraw = (const unsigned char*)d_in[2];
    const void*           embed   = d_in[3];
    const void*           Wq      = d_in[4];
    const void*           Wk      = d_in[5];
    const void*           Wv      = d_in[6];
    const void*           Wo      = d_in[7];
    const void*           We      = d_in[8];
    const void*           Wf      = d_in[9];
    const void*           bfb     = d_in[10];
    (void)d_ws; (void)ws_size; (void)in_sizes; (void)n_in; (void)out_size;

    (void)hipFuncSetAttribute((const void*)gnn_mfma<false>,
                              hipFuncAttributeMaxDynamicSharedMemorySize,
                              (int)SMEM2_BYTES);
    (void)hipFuncSetAttribute((const void*)gnn_mfma<true>,
                              hipFuncAttributeMaxDynamicSharedMemorySize,
                              (int)SMEM2_BYTES);

    transpose_w<<<dim3(15), dim3(256), 0, stream>>>(Wq, Wk, Wv, Wo, Wf);
    gnn_mfma<false><<<dim3(NBATCH), dim3(NTH), SMEM2_BYTES, stream>>>(
        coords, species, maskraw, embed, Wq, We, bfb, d_out);
    gnn_mfma<true><<<dim3(NBATCH), dim3(NTH), SMEM2_BYTES, stream>>>(
        coords, species, maskraw, embed, Wq, We, bfb, d_out);
}